// Round 1
// baseline (124.711 us; speedup 1.0000x reference)
//
#include <hip/hip_runtime.h>
#include <math.h>

#define NSTUFF 6
#define NCLS   10          // N_STUFF + N_THING
#define NBOX   32
#define NTHING 4
#define RR     28
#define HH     768
#define WW     704
#define NPIX   (HH * WW)   // 540672
#define BB     2
#define LL     (1 + NSTUFF + NBOX)   // 39
#define NEGV   (-100.0f)

// Tile choice (measured): 64x16 / 256 thr / 4 px-thread float4 = 1056 blocks,
// 52% occupancy -> 109.6 us end-to-end (R6). Doubling block count for 100%
// occupancy (R7: 64x8 / 128 thr, 4224 blocks) REGRESSED to 118.8 us —
// per-block fixed cost (setup+cull+hist flush+barriers) dominates over
// occupancy for this latency-profile. Keep 64x16/256.
#define TW 64
#define TH 16
#define TILES_X (WW / TW)            // 11
#define TILES_Y (HH / TH)            // 48
#define NTILES  (TILES_X * TILES_Y)  // 528 per batch
#define NHIST   (NBOX * NCLS + NSTUFF)

__device__ __forceinline__ float sigmoidf_(float x) {
    return 1.0f / (1.0f + expf(-x));
}

// ---------------------------------------------------------------------------
// K1: tiled fused logits + argmax + histograms.
// R8 restructure: box-OUTER / pixel-INNER. A thread's 4 pixels share one y,
// so all y-side work (bounds, bilinear row coords/weights, row pointers,
// thing-channel select) is computed ONCE per box instead of 4x, and the box
// params are read as 3x ds_read_b128 (int4/int4/float4) instead of 48 scalar
// LDS reads per box per thread. Sequential-argmax semantics preserved via the
// gap rule: boxes with no coverage at a pixel contribute exactly -0.0f; only
// the first box of a skipped run can win, and only while bv < 0 (note
// -0.0f < 0.0f is false, so a claim happens at most once per run).
// ---------------------------------------------------------------------------
__global__ __launch_bounds__(256) void k_fuse(
    const float* __restrict__ sem,   // [B][10][H][W]
    const float* __restrict__ roi,   // [B][32][4][28][28]
    const float* __restrict__ bbx,   // [B][32][4]
    const int*   __restrict__ cls,   // [B][32]
    uchar4*      __restrict__ pred8, // ws region, [B][H][W] bytes as uchar4
    int*         __restrict__ counts,
    int*         __restrict__ stuffh)
{
    const int b = blockIdx.y;
    __shared__ int4   sbA[NBOX];   // y0, x0, yme, xme
    __shared__ int4   sbB[NBOX];   // yie, xie, moff, cls
    __shared__ float4 sbF[NBOX];   // y0f, x0f, sy_scale, sx_scale
    __shared__ int   sh_list[NBOX];
    __shared__ int   sh_nbox;
    __shared__ int   sh_cnt[NHIST];

    const int t = threadIdx.x;
    const int tile = blockIdx.x;
    const int tx0 = (tile % TILES_X) * TW;
    const int ty0 = (tile / TILES_X) * TH;

    const int xq = tx0 + (t & 15) * 4;      // first of this thread's 4 pixels
    const int y  = ty0 + (t >> 4);
    const int p  = y * WW + xq;

    // wave 0: per-box setup + in-register tile cull. Issued BEFORE the bulk
    // sem loads so the bbx/cls latency hides under them.
    if (t < 64) {
        bool flag = false;
        if (t < NBOX) {
            const float* bbp = bbx + ((size_t)b * NBOX + t) * 4;
            float y0f = bbp[0], x0f = bbp[1], y1f = bbp[2], x1f = bbp[3];
            int y0 = (int)floorf(y0f), x0 = (int)floorf(x0f);
            int y1 = (int)floorf(y1f), x1 = (int)floorf(x1f);
            int yme = min(y1 + 1, HH), xme = min(x1 + 1, WW);
            int yie = (int)rintf(y1f) + 1, xie = (int)rintf(x1f) + 1;
            int c = cls[b * NBOX + t];
            sbA[t] = make_int4(y0, x0, yme, xme);
            sbB[t] = make_int4(yie, xie, (((b * NBOX + t) * NTHING) + c) * (RR * RR), c);
            float bh = (float)max(y1 - y0 + 1, 1);
            float bw = (float)max(x1 - x0 + 1, 1);
            sbF[t] = make_float4((float)y0, (float)x0, 28.0f / bh, 28.0f / bw);
            int uy = max(yme, yie), ux = max(xme, xie);
            flag = (y0 < ty0 + TH) && (uy > ty0) && (x0 < tx0 + TW) && (ux > tx0);
        }
        unsigned long long m = __ballot(flag);
        if (flag) {
            int pos = __popcll(m & (((unsigned long long)1 << t) - 1ull));
            sh_list[pos] = t;
        }
        if (t == 0) sh_nbox = __popcll(m);
    }

    // All 10 channels upfront as float4 (independent loads, one latency round)
    const float* semb = sem + (size_t)b * NCLS * NPIX;
    float4 s4[NCLS];
    #pragma unroll
    for (int c = 0; c < NCLS; ++c)
        s4[c] = *(const float4*)(semb + (size_t)c * NPIX + p);

    for (int i = t; i < NHIST; i += 256) sh_cnt[i] = 0;

    __syncthreads();

    const int nb = sh_nbox;
    const float yf = (float)y;

    // Per-pixel state: running argmax value/index + sem_pred.
    // stuff argmax (ch 0..5) is the prefix of the 10-ch sem argmax; strict >
    // keeps first-occurrence semantics for both.
    float bv[4]; int bi[4]; int sp[4];
    #pragma unroll
    for (int j = 0; j < 4; ++j) {
        float m0 = ((const float*)&s4[0])[j]; int i0 = 0;
        #pragma unroll
        for (int c = 1; c < NSTUFF; ++c) {
            float v = ((const float*)&s4[c])[j];
            if (v > m0) { m0 = v; i0 = c; }
        }
        bv[j] = m0; bi[j] = i0;
        float sb = m0; int spx = i0;
        #pragma unroll
        for (int c = NSTUFF; c < NCLS; ++c) {
            float v = ((const float*)&s4[c])[j];
            if (v > sb) { sb = v; spx = c; }
        }
        sp[j] = spx;
    }

    int prev = -1;
    for (int jb = 0; jb < nb; ++jb) {
        const int n = sh_list[jb];
        const int4 A  = sbA[n];   // y0, x0, yme, xme
        const int4 Bc = sbB[n];   // yie, xie, moff, cls
        const bool iny_m = (y >= max(A.x, 0)) & (y < A.z);
        const bool iny_i = (y >= A.x) & (y < Bc.x);
        // index claimed when bv<0 and this box contributes -0.0:
        // first of the skipped run if there is a gap, else this box itself.
        const int firstIdx = NSTUFF + ((n > prev + 1) ? (prev + 1) : n);

        if (!(iny_m | iny_i)) {
            // row-invalid: every pixel sees exactly -0.0 from this box (and
            // from any skipped boxes before it) -> pure gap-claim.
            #pragma unroll
            for (int j = 0; j < 4; ++j)
                if (bv[j] < 0.0f) { bv[j] = -0.0f; bi[j] = firstIdx; }
        } else {
            const float4 F = sbF[n];  // y0f, x0f, sy_scale, sx_scale
            // y-side once per box (valid only when iny_m; uses guarded)
            int ylo = 0, yhi = 0; float wy = 0.0f, omy = 1.0f;
            if (iny_m) {
                float sy = __fsub_rn(__fmul_rn(__fadd_rn(__fsub_rn(yf, F.x), 0.5f), F.z), 0.5f);
                sy = fminf(fmaxf(sy, 0.0f), 27.0f);
                ylo = (int)sy;
                yhi = min(ylo + 1, RR - 1);
                wy = __fsub_rn(sy, (float)ylo);
                omy = __fsub_rn(1.0f, wy);
            }
            const float* mrow = roi + Bc.z;
            const float* mlo = mrow + ylo * RR;
            const float* mhi = mrow + yhi * RR;
            const int c = Bc.w;
            float4 pz = (c == 0) ? s4[6] : (c == 1) ? s4[7] : (c == 2) ? s4[8] : s4[9];
            float pich[4] = {pz.x, pz.y, pz.z, pz.w};
            const int xm_lo = max(A.y, 0);

            #pragma unroll
            for (int j = 0; j < 4; ++j) {
                const int x = xq + j;
                // gap-claim for skipped run before this box
                if (n > prev + 1 && bv[j] < 0.0f) { bv[j] = -0.0f; bi[j] = NSTUFF + prev + 1; }
                const bool in_m = iny_m & (x >= xm_lo) & (x < A.w);
                const bool in_i = iny_i & (x >= A.y) & (x < Bc.y);
                if (in_m | in_i) {
                    float pm = NEGV;
                    if (in_m) {
                        float xf = (float)x;
                        float sx = __fsub_rn(__fmul_rn(__fadd_rn(__fsub_rn(xf, F.y), 0.5f), F.w), 0.5f);
                        sx = fminf(fmaxf(sx, 0.0f), 27.0f);
                        int xlo = (int)sx;
                        int xhi = min(xlo + 1, RR - 1);
                        float wx = __fsub_rn(sx, (float)xlo);
                        float omx = __fsub_rn(1.0f, wx);
                        float m00 = mlo[xlo], m01 = mlo[xhi];
                        float m10 = mhi[xlo], m11 = mhi[xhi];
                        float rl = __fadd_rn(__fmul_rn(m00, omy), __fmul_rn(m10, wy));
                        float rh = __fadd_rn(__fmul_rn(m01, omy), __fmul_rn(m11, wy));
                        pm = __fadd_rn(__fmul_rn(rl, omx), __fmul_rn(rh, wx));
                    }
                    float pi = in_i ? pich[j] : NEGV;
                    float v = __fmul_rn(__fadd_rn(sigmoidf_(pi), sigmoidf_(pm)), __fadd_rn(pi, pm));
                    if (v > bv[j]) { bv[j] = v; bi[j] = NSTUFF + n; }
                } else {
                    // pixel outside this box: contributes exactly -0.0
                    if (bv[j] < 0.0f) { bv[j] = -0.0f; bi[j] = firstIdx; }
                }
            }
        }
        prev = n;
    }
    // trailing skipped run
    #pragma unroll
    for (int j = 0; j < 4; ++j)
        if (prev < NBOX - 1 && bv[j] < 0.0f) bi[j] = NSTUFF + prev + 1;

    uchar4 pv;
    pv.x = (unsigned char)bi[0]; pv.y = (unsigned char)bi[1];
    pv.z = (unsigned char)bi[2]; pv.w = (unsigned char)bi[3];
    pred8[((size_t)b * NPIX + p) >> 2] = pv;

    // histogram: ballot-aggregate stuff bins; scatter-atomic instance pixels
    const int lane = t & 63;
    #pragma unroll
    for (int s = 0; s < NSTUFF; ++s) {
        int c = 0;
        #pragma unroll
        for (int j = 0; j < 4; ++j) c += __popcll(__ballot(bi[j] == s));
        if (lane == 0 && c) atomicAdd(&sh_cnt[NBOX * NCLS + s], c);
    }
    #pragma unroll
    for (int j = 0; j < 4; ++j)
        if (bi[j] >= NSTUFF) atomicAdd(&sh_cnt[(bi[j] - NSTUFF) * NCLS + sp[j]], 1);

    __syncthreads();
    for (int i = t; i < NHIST; i += 256) {
        int v = sh_cnt[i];
        if (v) {
            if (i < NBOX * NCLS) atomicAdd(&counts[b * NBOX * NCLS + i], v);
            else                 atomicAdd(&stuffh[b * NSTUFF + (i - NBOX * NCLS)], v);
        }
    }
}

// ---------------------------------------------------------------------------
// K2: fused label + seam remap. Pred bytes are loaded BEFORE the LUT barrier
// (independent of it) so wave-0's LUT recompute latency is hidden behind the
// global load. Ranks are pure functions of ballot masks. Block (0,b) also
// writes po_cls / po_iscrowd.
// ---------------------------------------------------------------------------
__global__ __launch_bounds__(256) void k_relabel(
    const int*    __restrict__ counts,
    const int*    __restrict__ stuffh,
    const int*    __restrict__ cls,
    const uchar4* __restrict__ pred8,
    int*          __restrict__ out)
{
    const int b = blockIdx.y;
    const int t = threadIdx.x;
    __shared__ int slut[NSTUFF + NBOX];
    __shared__ int l_sh[NSTUFF];
    __shared__ int l_ih[NBOX];
    __shared__ int l_isem[NBOX];
    __shared__ int l_co[LL];

    // issue the pred load first (independent of the LUT)
    const size_t q = (size_t)b * (NPIX / 4) + (size_t)blockIdx.x * 256 + t;
    const uchar4 v = pred8[q];

    int  ssum = 0, mj = 0, semv = 0, idx = -1;
    bool pres = false, ts = false;

    if (t < 64) {
        if (t < NSTUFF) l_sh[t] = stuffh[b * NSTUFF + t];
        if (t < NBOX)  { l_ih[t] = 0; l_isem[t] = 255; }
        if (t < LL)      l_co[t] = 255;

        if (t < NBOX) {
            const int* C = counts + ((size_t)b * NBOX + t) * NCLS;
            int c[NCLS];
            #pragma unroll
            for (int i = 0; i < NCLS; ++i) c[i] = C[i];
            int m = c[0]; mj = 0; ssum = c[0];
            #pragma unroll
            for (int i = 1; i < NCLS; ++i) {
                ssum += c[i];
                if (c[i] > m) { m = c[i]; mj = i; }
            }
            pres = ssum > 0;
            int thing = cls[b * NBOX + t] + NSTUFF;
            ts = pres && (mj != thing) && (2 * m >= ssum) && (mj < NSTUFF);
            semv = ts ? mj : thing;
        }
        unsigned long long pm = __ballot(pres);
        idx = __popcll(pm & (((unsigned long long)2 << t) - 1ull)) - 1;

        if (t < NBOX && pres &&  ts) atomicAdd(&l_sh[mj], ssum);
        if (t < NBOX && pres && !ts) { atomicAdd(&l_ih[idx], ssum); l_isem[idx] = semv; }
    }
    __syncthreads();

    if (t < 64) {
        bool spres = (t < NSTUFF) && (l_sh[t] > 0);
        unsigned long long sm = __ballot(spres);
        const int nst = __popcll(sm);
        bool ipres = (t < NBOX) && (l_ih[t] > 0);
        unsigned long long im = __ballot(ipres);

        auto srank = [&](int c) { return __popcll(sm & (((unsigned long long)2 << c) - 1ull)) - 1; };
        auto irank = [&](int j) { return __popcll(im & (((unsigned long long)2 << j) - 1ull)) - 1; };

        if (t < NSTUFF) slut[t] = 1 + srank(t);
        if (t < NBOX) {
            int q2 = idx < 0 ? 0 : idx;
            slut[NSTUFF + t] = ts ? (1 + srank(mj)) : (1 + nst + irank(q2));
        }
        if (spres) l_co[1 + srank(t)] = t;
        if (ipres) l_co[1 + nst + irank(t)] = l_isem[t];
    }
    __syncthreads();

    int4 o;
    o.x = slut[v.x];
    o.y = slut[v.y];
    o.z = slut[v.z];
    o.w = slut[v.w];
    ((int4*)out)[q] = o;

    if (blockIdx.x == 0 && t < LL) {
        int* ocls = out + (size_t)BB * NPIX + b * LL;
        int* ocrd = out + (size_t)BB * NPIX + BB * LL + b * LL;
        ocls[t] = l_co[t];
        ocrd[t] = 0;
    }
}

extern "C" void kernel_launch(void* const* d_in, const int* in_sizes, int n_in,
                              void* d_out, int out_size, void* d_ws, size_t ws_size,
                              hipStream_t stream) {
    (void)in_sizes; (void)n_in; (void)out_size; (void)ws_size;
    const float* sem = (const float*)d_in[0];
    const float* roi = (const float*)d_in[1];
    const float* bbx = (const float*)d_in[2];
    const int*   cls = (const int*)d_in[3];
    int* out = (int*)d_out;

    int* counts = (int*)d_ws;                        // [B][32][10]
    int* stuffh = counts + BB * NBOX * NCLS;         // [B][6]
    // 652 ints = 2608 B (16B-aligned); pred bytes follow
    uchar4* pred8 = (uchar4*)(stuffh + BB * NSTUFF); // [B*NPIX] bytes

    hipMemsetAsync(d_ws, 0, (BB * NBOX * NCLS + BB * NSTUFF) * sizeof(int), stream);

    dim3 g1(NTILES, BB);
    k_fuse<<<g1, 256, 0, stream>>>(sem, roi, bbx, cls, pred8, counts, stuffh);
    dim3 g2(NPIX / 1024, BB);   // 528 blocks/batch, 256 thr x 4 px
    k_relabel<<<g2, 256, 0, stream>>>(counts, stuffh, cls, pred8, out);
}

// Round 3
// 120.739 us; speedup vs baseline: 1.0329x; 1.0329x over previous
//
#include <hip/hip_runtime.h>
#include <math.h>

#define NSTUFF 6
#define NCLS   10          // N_STUFF + N_THING
#define NBOX   32
#define NTHING 4
#define RR     28
#define HH     768
#define WW     704
#define NPIX   (HH * WW)   // 540672
#define BB     2
#define LL     (1 + NSTUFF + NBOX)   // 39
#define NEGV   (-100.0f)

// Tile choice (measured): 64x16 / 256 thr / 4 px-thread float4 = 1056 blocks.
// R7: 128-thr blocks regressed (per-block fixed cost). Keep 64x16/256.
#define TW 64
#define TH 16
#define TILES_X (WW / TW)            // 11
#define TILES_Y (HH / TH)            // 48
#define NTILES  (TILES_X * TILES_Y)  // 528 per batch
#define NHIST   (NBOX * NCLS + NSTUFF)

__device__ __forceinline__ float sigmoidf_(float x) {
    return 1.0f / (1.0f + expf(-x));
}

// ---------------------------------------------------------------------------
// K1: tiled fused logits + argmax + histograms (box-outer/pixel-inner).
// R10: __launch_bounds__(256, 4). R1's counters showed VGPR_Count=44 while
// the s4[10] float4 block alone needs 40 live VGPRs across the box loop ->
// the compiler was splitting the upfront sem load into several dependent
// latency rounds (k_fuse 43us at only 26% HBM, 14% VALU = stall-bound).
// Min-4-waves/EU caps VGPRs at ~128, letting all 10 loads stay in flight in
// ONE latency round. Occupancy drops (8->4 waves/SIMD) by design: this
// kernel needs MLP, not TLP.
// Sequential-argmax semantics preserved via the gap rule: boxes with no
// coverage at a pixel contribute exactly -0.0f; only the first box of a
// skipped run can win, and only while bv < 0 (-0.0f < 0.0f is false, so a
// claim happens at most once per run).
// ---------------------------------------------------------------------------
__global__ __launch_bounds__(256, 4) void k_fuse(
    const float* __restrict__ sem,   // [B][10][H][W]
    const float* __restrict__ roi,   // [B][32][4][28][28]
    const float* __restrict__ bbx,   // [B][32][4]
    const int*   __restrict__ cls,   // [B][32]
    uchar4*      __restrict__ pred8, // ws region, [B][H][W] bytes as uchar4
    int*         __restrict__ counts,
    int*         __restrict__ stuffh)
{
    const int b = blockIdx.y;
    __shared__ int4   sbA[NBOX];   // y0, x0, yme, xme
    __shared__ int4   sbB[NBOX];   // yie, xie, moff, cls
    __shared__ float4 sbF[NBOX];   // y0f, x0f, sy_scale, sx_scale
    __shared__ int   sh_list[NBOX];
    __shared__ int   sh_nbox;
    __shared__ int   sh_cnt[NHIST];

    const int t = threadIdx.x;
    const int tile = blockIdx.x;
    const int tx0 = (tile % TILES_X) * TW;
    const int ty0 = (tile / TILES_X) * TH;

    const int xq = tx0 + (t & 15) * 4;      // first of this thread's 4 pixels
    const int y  = ty0 + (t >> 4);
    const int p  = y * WW + xq;

    // Issue the bulk sem loads FIRST (latency-bound phase): 10 channels as
    // independent float4 loads, one latency round. Everything below overlaps
    // with them in flight.
    const float* semb = sem + (size_t)b * NCLS * NPIX;
    float4 s4[NCLS];
    #pragma unroll
    for (int c = 0; c < NCLS; ++c)
        s4[c] = *(const float4*)(semb + (size_t)c * NPIX + p);

    // wave 0: per-box setup + in-register tile cull (overlaps sem loads)
    if (t < 64) {
        bool flag = false;
        if (t < NBOX) {
            const float* bbp = bbx + ((size_t)b * NBOX + t) * 4;
            float y0f = bbp[0], x0f = bbp[1], y1f = bbp[2], x1f = bbp[3];
            int y0 = (int)floorf(y0f), x0 = (int)floorf(x0f);
            int y1 = (int)floorf(y1f), x1 = (int)floorf(x1f);
            int yme = min(y1 + 1, HH), xme = min(x1 + 1, WW);
            int yie = (int)rintf(y1f) + 1, xie = (int)rintf(x1f) + 1;
            int c = cls[b * NBOX + t];
            sbA[t] = make_int4(y0, x0, yme, xme);
            sbB[t] = make_int4(yie, xie, (((b * NBOX + t) * NTHING) + c) * (RR * RR), c);
            float bh = (float)max(y1 - y0 + 1, 1);
            float bw = (float)max(x1 - x0 + 1, 1);
            sbF[t] = make_float4((float)y0, (float)x0, 28.0f / bh, 28.0f / bw);
            int uy = max(yme, yie), ux = max(xme, xie);
            flag = (y0 < ty0 + TH) && (uy > ty0) && (x0 < tx0 + TW) && (ux > tx0);
        }
        unsigned long long m = __ballot(flag);
        if (flag) {
            int pos = __popcll(m & (((unsigned long long)1 << t) - 1ull));
            sh_list[pos] = t;
        }
        if (t == 0) sh_nbox = __popcll(m);
    }

    for (int i = t; i < NHIST; i += 256) sh_cnt[i] = 0;

    // argmax prologue (stalls on the sem loads; wave 0's setup latency is
    // hidden under them). stuff argmax (ch 0..5) is the prefix of the 10-ch
    // sem argmax; strict > keeps first-occurrence semantics for both.
    float bv[4]; int bi[4]; int sp[4];
    #pragma unroll
    for (int j = 0; j < 4; ++j) {
        float m0 = ((const float*)&s4[0])[j]; int i0 = 0;
        #pragma unroll
        for (int c = 1; c < NSTUFF; ++c) {
            float v = ((const float*)&s4[c])[j];
            if (v > m0) { m0 = v; i0 = c; }
        }
        bv[j] = m0; bi[j] = i0;
        float sb = m0; int spx = i0;
        #pragma unroll
        for (int c = NSTUFF; c < NCLS; ++c) {
            float v = ((const float*)&s4[c])[j];
            if (v > sb) { sb = v; spx = c; }
        }
        sp[j] = spx;
    }

    __syncthreads();

    const int nb = sh_nbox;
    const float yf = (float)y;

    int prev = -1;
    for (int jb = 0; jb < nb; ++jb) {
        const int n = sh_list[jb];
        const int4 A  = sbA[n];   // y0, x0, yme, xme
        const int4 Bc = sbB[n];   // yie, xie, moff, cls
        const bool iny_m = (y >= max(A.x, 0)) & (y < A.z);
        const bool iny_i = (y >= A.x) & (y < Bc.x);
        // index claimed when bv<0 and this box contributes -0.0:
        // first of the skipped run if there is a gap, else this box itself.
        const int firstIdx = NSTUFF + ((n > prev + 1) ? (prev + 1) : n);

        if (!(iny_m | iny_i)) {
            // row-invalid: every pixel sees exactly -0.0 from this box (and
            // from any skipped boxes before it) -> pure gap-claim.
            #pragma unroll
            for (int j = 0; j < 4; ++j)
                if (bv[j] < 0.0f) { bv[j] = -0.0f; bi[j] = firstIdx; }
        } else {
            const float4 F = sbF[n];  // y0f, x0f, sy_scale, sx_scale
            // y-side once per box (valid only when iny_m; uses guarded)
            int ylo = 0, yhi = 0; float wy = 0.0f, omy = 1.0f;
            if (iny_m) {
                float sy = __fsub_rn(__fmul_rn(__fadd_rn(__fsub_rn(yf, F.x), 0.5f), F.z), 0.5f);
                sy = fminf(fmaxf(sy, 0.0f), 27.0f);
                ylo = (int)sy;
                yhi = min(ylo + 1, RR - 1);
                wy = __fsub_rn(sy, (float)ylo);
                omy = __fsub_rn(1.0f, wy);
            }
            const float* mrow = roi + Bc.z;
            const float* mlo = mrow + ylo * RR;
            const float* mhi = mrow + yhi * RR;
            const int c = Bc.w;
            float4 pz = (c == 0) ? s4[6] : (c == 1) ? s4[7] : (c == 2) ? s4[8] : s4[9];
            float pich[4] = {pz.x, pz.y, pz.z, pz.w};
            const int xm_lo = max(A.y, 0);

            #pragma unroll
            for (int j = 0; j < 4; ++j) {
                const int x = xq + j;
                // gap-claim for skipped run before this box
                if (n > prev + 1 && bv[j] < 0.0f) { bv[j] = -0.0f; bi[j] = NSTUFF + prev + 1; }
                const bool in_m = iny_m & (x >= xm_lo) & (x < A.w);
                const bool in_i = iny_i & (x >= A.y) & (x < Bc.y);
                if (in_m | in_i) {
                    float pm = NEGV;
                    if (in_m) {
                        float xf = (float)x;
                        float sx = __fsub_rn(__fmul_rn(__fadd_rn(__fsub_rn(xf, F.y), 0.5f), F.w), 0.5f);
                        sx = fminf(fmaxf(sx, 0.0f), 27.0f);
                        int xlo = (int)sx;
                        int xhi = min(xlo + 1, RR - 1);
                        float wx = __fsub_rn(sx, (float)xlo);
                        float omx = __fsub_rn(1.0f, wx);
                        float m00 = mlo[xlo], m01 = mlo[xhi];
                        float m10 = mhi[xlo], m11 = mhi[xhi];
                        float rl = __fadd_rn(__fmul_rn(m00, omy), __fmul_rn(m10, wy));
                        float rh = __fadd_rn(__fmul_rn(m01, omy), __fmul_rn(m11, wy));
                        pm = __fadd_rn(__fmul_rn(rl, omx), __fmul_rn(rh, wx));
                    }
                    float pi = in_i ? pich[j] : NEGV;
                    float v = __fmul_rn(__fadd_rn(sigmoidf_(pi), sigmoidf_(pm)), __fadd_rn(pi, pm));
                    if (v > bv[j]) { bv[j] = v; bi[j] = NSTUFF + n; }
                } else {
                    // pixel outside this box: contributes exactly -0.0
                    if (bv[j] < 0.0f) { bv[j] = -0.0f; bi[j] = firstIdx; }
                }
            }
        }
        prev = n;
    }
    // trailing skipped run
    #pragma unroll
    for (int j = 0; j < 4; ++j)
        if (prev < NBOX - 1 && bv[j] < 0.0f) bi[j] = NSTUFF + prev + 1;

    uchar4 pv;
    pv.x = (unsigned char)bi[0]; pv.y = (unsigned char)bi[1];
    pv.z = (unsigned char)bi[2]; pv.w = (unsigned char)bi[3];
    pred8[((size_t)b * NPIX + p) >> 2] = pv;

    // histogram: ballot-aggregate stuff bins; scatter-atomic instance pixels
    const int lane = t & 63;
    #pragma unroll
    for (int s = 0; s < NSTUFF; ++s) {
        int c = 0;
        #pragma unroll
        for (int j = 0; j < 4; ++j) c += __popcll(__ballot(bi[j] == s));
        if (lane == 0 && c) atomicAdd(&sh_cnt[NBOX * NCLS + s], c);
    }
    #pragma unroll
    for (int j = 0; j < 4; ++j)
        if (bi[j] >= NSTUFF) atomicAdd(&sh_cnt[(bi[j] - NSTUFF) * NCLS + sp[j]], 1);

    __syncthreads();
    for (int i = t; i < NHIST; i += 256) {
        int v = sh_cnt[i];
        if (v) {
            if (i < NBOX * NCLS) atomicAdd(&counts[b * NBOX * NCLS + i], v);
            else                 atomicAdd(&stuffh[b * NSTUFF + (i - NBOX * NCLS)], v);
        }
    }
}

// ---------------------------------------------------------------------------
// K2: fused label + seam remap. Pred bytes are loaded BEFORE the LUT barrier
// (independent of it) so wave-0's LUT recompute latency is hidden behind the
// global load. Ranks are pure functions of ballot masks. Block (0,b) also
// writes po_cls / po_iscrowd.
// ---------------------------------------------------------------------------
__global__ __launch_bounds__(256) void k_relabel(
    const int*    __restrict__ counts,
    const int*    __restrict__ stuffh,
    const int*    __restrict__ cls,
    const uchar4* __restrict__ pred8,
    int*          __restrict__ out)
{
    const int b = blockIdx.y;
    const int t = threadIdx.x;
    __shared__ int slut[NSTUFF + NBOX];
    __shared__ int l_sh[NSTUFF];
    __shared__ int l_ih[NBOX];
    __shared__ int l_isem[NBOX];
    __shared__ int l_co[LL];

    // issue the pred load first (independent of the LUT)
    const size_t q = (size_t)b * (NPIX / 4) + (size_t)blockIdx.x * 256 + t;
    const uchar4 v = pred8[q];

    int  ssum = 0, mj = 0, semv = 0, idx = -1;
    bool pres = false, ts = false;

    if (t < 64) {
        if (t < NSTUFF) l_sh[t] = stuffh[b * NSTUFF + t];
        if (t < NBOX)  { l_ih[t] = 0; l_isem[t] = 255; }
        if (t < LL)      l_co[t] = 255;

        if (t < NBOX) {
            const int* C = counts + ((size_t)b * NBOX + t) * NCLS;
            int c[NCLS];
            #pragma unroll
            for (int i = 0; i < NCLS; ++i) c[i] = C[i];
            int m = c[0]; mj = 0; ssum = c[0];
            #pragma unroll
            for (int i = 1; i < NCLS; ++i) {
                ssum += c[i];
                if (c[i] > m) { m = c[i]; mj = i; }
            }
            pres = ssum > 0;
            int thing = cls[b * NBOX + t] + NSTUFF;
            ts = pres && (mj != thing) && (2 * m >= ssum) && (mj < NSTUFF);
            semv = ts ? mj : thing;
        }
        unsigned long long pm = __ballot(pres);
        idx = __popcll(pm & (((unsigned long long)2 << t) - 1ull)) - 1;

        if (t < NBOX && pres &&  ts) atomicAdd(&l_sh[mj], ssum);
        if (t < NBOX && pres && !ts) { atomicAdd(&l_ih[idx], ssum); l_isem[idx] = semv; }
    }
    __syncthreads();

    if (t < 64) {
        bool spres = (t < NSTUFF) && (l_sh[t] > 0);
        unsigned long long sm = __ballot(spres);
        const int nst = __popcll(sm);
        bool ipres = (t < NBOX) && (l_ih[t] > 0);
        unsigned long long im = __ballot(ipres);

        auto srank = [&](int c) { return __popcll(sm & (((unsigned long long)2 << c) - 1ull)) - 1; };
        auto irank = [&](int j) { return __popcll(im & (((unsigned long long)2 << j) - 1ull)) - 1; };

        if (t < NSTUFF) slut[t] = 1 + srank(t);
        if (t < NBOX) {
            int q2 = idx < 0 ? 0 : idx;
            slut[NSTUFF + t] = ts ? (1 + srank(mj)) : (1 + nst + irank(q2));
        }
        if (spres) l_co[1 + srank(t)] = t;
        if (ipres) l_co[1 + nst + irank(t)] = l_isem[t];
    }
    __syncthreads();

    int4 o;
    o.x = slut[v.x];
    o.y = slut[v.y];
    o.z = slut[v.z];
    o.w = slut[v.w];
    ((int4*)out)[q] = o;

    if (blockIdx.x == 0 && t < LL) {
        int* ocls = out + (size_t)BB * NPIX + b * LL;
        int* ocrd = out + (size_t)BB * NPIX + BB * LL + b * LL;
        ocls[t] = l_co[t];
        ocrd[t] = 0;
    }
}

extern "C" void kernel_launch(void* const* d_in, const int* in_sizes, int n_in,
                              void* d_out, int out_size, void* d_ws, size_t ws_size,
                              hipStream_t stream) {
    (void)in_sizes; (void)n_in; (void)out_size; (void)ws_size;
    const float* sem = (const float*)d_in[0];
    const float* roi = (const float*)d_in[1];
    const float* bbx = (const float*)d_in[2];
    const int*   cls = (const int*)d_in[3];
    int* out = (int*)d_out;

    int* counts = (int*)d_ws;                        // [B][32][10]
    int* stuffh = counts + BB * NBOX * NCLS;         // [B][6]
    // 652 ints = 2608 B (16B-aligned); pred bytes follow
    uchar4* pred8 = (uchar4*)(stuffh + BB * NSTUFF); // [B*NPIX] bytes

    hipMemsetAsync(d_ws, 0, (BB * NBOX * NCLS + BB * NSTUFF) * sizeof(int), stream);

    dim3 g1(NTILES, BB);
    k_fuse<<<g1, 256, 0, stream>>>(sem, roi, bbx, cls, pred8, counts, stuffh);
    dim3 g2(NPIX / 1024, BB);   // 528 blocks/batch, 256 thr x 4 px
    k_relabel<<<g2, 256, 0, stream>>>(counts, stuffh, cls, pred8, out);
}

// Round 4
// 110.079 us; speedup vs baseline: 1.1329x; 1.0968x over previous
//
#include <hip/hip_runtime.h>
#include <math.h>

#define NSTUFF 6
#define NCLS   10          // N_STUFF + N_THING
#define NBOX   32
#define NTHING 4
#define RR     28
#define HH     768
#define WW     704
#define NPIX   (HH * WW)   // 540672
#define BB     2
#define LL     (1 + NSTUFF + NBOX)   // 39
#define NEGV   (-100.0f)

// Tile choice (measured): 64x16 / 256 thr / 4 px-thread float4 = 1056 blocks,
// 52% occupancy -> 109.6 us end-to-end (R6). Doubling block count for 100%
// occupancy (R7: 64x8 / 128 thr, 4224 blocks) REGRESSED to 118.8 us.
// R8/R10 box-outer restructure REGRESSED (124.7 / 120.7 vs 108.6): VALUBusy
// was 14% — instruction count was never the bottleneck; the merged loop also
// lost the independence of the four per-pixel box-loop chains. Keep
// pixel-outer doPix x4.
#define TW 64
#define TH 16
#define TILES_X (WW / TW)            // 11
#define TILES_Y (HH / TH)            // 48
#define NTILES  (TILES_X * TILES_Y)  // 528 per batch
#define NHIST   (NBOX * NCLS + NSTUFF)

__device__ __forceinline__ float sigmoidf_(float x) {
    return 1.0f / (1.0f + expf(-x));
}

// ---------------------------------------------------------------------------
// K1: tiled fused logits + argmax + histograms. 4 px/thread via float4 sem
// loads (all 10 channels upfront -> one latency round). Per-tile box cull
// in-register by wave 0. Winner index (0..37) stored as uchar4 into ws.
// Sequential-argmax semantics preserved via the gap rule (skipped boxes
// contribute exactly -0.0f; only the first box of a skipped run can win, and
// only while bv < 0).
// R11: __launch_bounds__(256, 4). At default bounds the compiler targets 8
// waves/EU (VGPR<=64, measured 44) — s4[10] alone is 40 live VGPRs, so the
// four independent doPix box-loop chains were forced to run strictly
// back-to-back. The 128-VGPR cap lets the compiler keep s4 resident and
// overlap the chains (MLP-for-TLP trade; at 26% HBM / 14% VALU there is
// ample headroom for fewer waves).
// ---------------------------------------------------------------------------
__global__ __launch_bounds__(256, 4) void k_fuse(
    const float* __restrict__ sem,   // [B][10][H][W]
    const float* __restrict__ roi,   // [B][32][4][28][28]
    const float* __restrict__ bbx,   // [B][32][4]
    const int*   __restrict__ cls,   // [B][32]
    uchar4*      __restrict__ pred8, // ws region, [B][H][W] bytes as uchar4
    int*         __restrict__ counts,
    int*         __restrict__ stuffh)
{
    const int b = blockIdx.y;
    __shared__ int   sh_y0[NBOX], sh_x0[NBOX], sh_yme[NBOX], sh_xme[NBOX];
    __shared__ int   sh_yie[NBOX], sh_xie[NBOX], sh_moff[NBOX], sh_cls[NBOX];
    __shared__ float sh_y0f[NBOX], sh_x0f[NBOX], sh_sy[NBOX], sh_sx[NBOX];
    __shared__ int   sh_list[NBOX];
    __shared__ int   sh_nbox;
    __shared__ int   sh_cnt[NHIST];

    const int t = threadIdx.x;
    const int tile = blockIdx.x;
    const int tx0 = (tile % TILES_X) * TW;
    const int ty0 = (tile / TILES_X) * TH;

    const int xq = tx0 + (t & 15) * 4;      // first of this thread's 4 pixels
    const int y  = ty0 + (t >> 4);
    const int p  = y * WW + xq;

    // All 10 channels upfront as float4 (independent loads, one latency round)
    const float* semb = sem + (size_t)b * NCLS * NPIX;
    float4 s4[NCLS];
    #pragma unroll
    for (int c = 0; c < NCLS; ++c)
        s4[c] = *(const float4*)(semb + (size_t)c * NPIX + p);

    for (int i = t; i < NHIST; i += 256) sh_cnt[i] = 0;

    // wave 0: per-box setup + in-register tile cull
    if (t < 64) {
        bool flag = false;
        if (t < NBOX) {
            const float* bbp = bbx + ((size_t)b * NBOX + t) * 4;
            float y0f = bbp[0], x0f = bbp[1], y1f = bbp[2], x1f = bbp[3];
            int y0 = (int)floorf(y0f), x0 = (int)floorf(x0f);
            int y1 = (int)floorf(y1f), x1 = (int)floorf(x1f);
            int yme = min(y1 + 1, HH), xme = min(x1 + 1, WW);
            int yie = (int)rintf(y1f) + 1, xie = (int)rintf(x1f) + 1;
            sh_y0[t] = y0;  sh_x0[t] = x0;
            sh_yme[t] = yme; sh_xme[t] = xme;
            sh_yie[t] = yie; sh_xie[t] = xie;
            sh_y0f[t] = (float)y0; sh_x0f[t] = (float)x0;
            float hh = (float)max(y1 - y0 + 1, 1);
            float ww = (float)max(x1 - x0 + 1, 1);
            sh_sy[t] = 28.0f / hh;  sh_sx[t] = 28.0f / ww;
            int c = cls[b * NBOX + t];
            sh_cls[t] = c;
            sh_moff[t] = (((b * NBOX + t) * NTHING) + c) * (RR * RR);
            int uy = max(yme, yie), ux = max(xme, xie);
            flag = (y0 < ty0 + TH) && (uy > ty0) && (x0 < tx0 + TW) && (ux > tx0);
        }
        unsigned long long m = __ballot(flag);
        if (flag) {
            int pos = __popcll(m & (((unsigned long long)1 << t) - 1ull));
            sh_list[pos] = t;
        }
        if (t == 0) sh_nbox = __popcll(m);
    }
    __syncthreads();

    const int nb = sh_nbox;

    auto doPix = [&](const float* s, int y_, int x_, int& bi_o, int& sp_o) {
        const float yf = (float)y_, xf = (float)x_;
        // sem_pred: full 10-channel argmax, first-occurrence ties
        float sb = s[0]; int sp = 0;
        #pragma unroll
        for (int c = 1; c < NCLS; ++c) if (s[c] > sb) { sb = s[c]; sp = c; }

        // stuff argmax
        float bv = s[0]; int bi = 0;
        #pragma unroll
        for (int c = 1; c < NSTUFF; ++c) if (s[c] > bv) { bv = s[c]; bi = c; }

        int prev = -1;
        for (int j = 0; j < nb; ++j) {
            const int n = sh_list[j];
            if (n > prev + 1 && bv < 0.0f) { bv = -0.0f; bi = NSTUFF + prev + 1; }
            const bool in_m = (y_ >= max(sh_y0[n], 0)) & (y_ < sh_yme[n]) &
                              (x_ >= max(sh_x0[n], 0)) & (x_ < sh_xme[n]);
            const bool in_i = (y_ >= sh_y0[n]) & (y_ < sh_yie[n]) &
                              (x_ >= sh_x0[n]) & (x_ < sh_xie[n]);
            float v;
            if (in_m | in_i) {
                float pm = NEGV;
                if (in_m) {
                    float sy = __fsub_rn(__fmul_rn(__fadd_rn(__fsub_rn(yf, sh_y0f[n]), 0.5f), sh_sy[n]), 0.5f);
                    sy = fminf(fmaxf(sy, 0.0f), 27.0f);
                    int ylo = (int)sy;
                    int yhi = min(ylo + 1, RR - 1);
                    float wy = __fsub_rn(sy, (float)ylo);
                    float sx = __fsub_rn(__fmul_rn(__fadd_rn(__fsub_rn(xf, sh_x0f[n]), 0.5f), sh_sx[n]), 0.5f);
                    sx = fminf(fmaxf(sx, 0.0f), 27.0f);
                    int xlo = (int)sx;
                    int xhi = min(xlo + 1, RR - 1);
                    float wx = __fsub_rn(sx, (float)xlo);
                    const float* m = roi + sh_moff[n];
                    float m00 = m[ylo * RR + xlo], m01 = m[ylo * RR + xhi];
                    float m10 = m[yhi * RR + xlo], m11 = m[yhi * RR + xhi];
                    float omy = __fsub_rn(1.0f, wy), omx = __fsub_rn(1.0f, wx);
                    float rl = __fadd_rn(__fmul_rn(m00, omy), __fmul_rn(m10, wy));
                    float rh = __fadd_rn(__fmul_rn(m01, omy), __fmul_rn(m11, wy));
                    pm = __fadd_rn(__fmul_rn(rl, omx), __fmul_rn(rh, wx));
                }
                float pi = NEGV;
                if (in_i) {
                    int c = sh_cls[n];
                    pi = (c == 0) ? s[6] : (c == 1) ? s[7] : (c == 2) ? s[8] : s[9];
                }
                v = __fmul_rn(__fadd_rn(sigmoidf_(pi), sigmoidf_(pm)), __fadd_rn(pi, pm));
            } else {
                v = -0.0f;
            }
            if (v > bv) { bv = v; bi = NSTUFF + n; }
            prev = n;
        }
        if (prev < NBOX - 1 && bv < 0.0f) { bi = NSTUFF + prev + 1; }
        bi_o = bi; sp_o = sp;
    };

    int bis[4], sps[4];
    #pragma unroll
    for (int j = 0; j < 4; ++j) {
        float s[NCLS];
        #pragma unroll
        for (int c = 0; c < NCLS; ++c) s[c] = ((const float*)&s4[c])[j];
        doPix(s, y, xq + j, bis[j], sps[j]);
    }

    uchar4 pv;
    pv.x = (unsigned char)bis[0]; pv.y = (unsigned char)bis[1];
    pv.z = (unsigned char)bis[2]; pv.w = (unsigned char)bis[3];
    pred8[((size_t)b * NPIX + p) >> 2] = pv;

    // histogram: ballot-aggregate stuff bins; scatter-atomic instance pixels
    const int lane = t & 63;
    #pragma unroll
    for (int s = 0; s < NSTUFF; ++s) {
        int c = 0;
        #pragma unroll
        for (int j = 0; j < 4; ++j) c += __popcll(__ballot(bis[j] == s));
        if (lane == 0 && c) atomicAdd(&sh_cnt[NBOX * NCLS + s], c);
    }
    #pragma unroll
    for (int j = 0; j < 4; ++j)
        if (bis[j] >= NSTUFF) atomicAdd(&sh_cnt[(bis[j] - NSTUFF) * NCLS + sps[j]], 1);

    __syncthreads();
    for (int i = t; i < NHIST; i += 256) {
        int v = sh_cnt[i];
        if (v) {
            if (i < NBOX * NCLS) atomicAdd(&counts[b * NBOX * NCLS + i], v);
            else                 atomicAdd(&stuffh[b * NSTUFF + (i - NBOX * NCLS)], v);
        }
    }
}

// ---------------------------------------------------------------------------
// K2: fused label + seam remap. Pred bytes are loaded BEFORE the LUT barrier
// (independent of it) so wave-0's LUT recompute latency is hidden behind the
// global load. Ranks are pure functions of ballot masks. Block (0,b) also
// writes po_cls / po_iscrowd.
// ---------------------------------------------------------------------------
__global__ __launch_bounds__(256) void k_relabel(
    const int*    __restrict__ counts,
    const int*    __restrict__ stuffh,
    const int*    __restrict__ cls,
    const uchar4* __restrict__ pred8,
    int*          __restrict__ out)
{
    const int b = blockIdx.y;
    const int t = threadIdx.x;
    __shared__ int slut[NSTUFF + NBOX];
    __shared__ int l_sh[NSTUFF];
    __shared__ int l_ih[NBOX];
    __shared__ int l_isem[NBOX];
    __shared__ int l_co[LL];

    // issue the pred load first (independent of the LUT)
    const size_t q = (size_t)b * (NPIX / 4) + (size_t)blockIdx.x * 256 + t;
    const uchar4 v = pred8[q];

    int  ssum = 0, mj = 0, semv = 0, idx = -1;
    bool pres = false, ts = false;

    if (t < 64) {
        if (t < NSTUFF) l_sh[t] = stuffh[b * NSTUFF + t];
        if (t < NBOX)  { l_ih[t] = 0; l_isem[t] = 255; }
        if (t < LL)      l_co[t] = 255;

        if (t < NBOX) {
            const int* C = counts + ((size_t)b * NBOX + t) * NCLS;
            int c[NCLS];
            #pragma unroll
            for (int i = 0; i < NCLS; ++i) c[i] = C[i];
            int m = c[0]; mj = 0; ssum = c[0];
            #pragma unroll
            for (int i = 1; i < NCLS; ++i) {
                ssum += c[i];
                if (c[i] > m) { m = c[i]; mj = i; }
            }
            pres = ssum > 0;
            int thing = cls[b * NBOX + t] + NSTUFF;
            ts = pres && (mj != thing) && (2 * m >= ssum) && (mj < NSTUFF);
            semv = ts ? mj : thing;
        }
        unsigned long long pm = __ballot(pres);
        idx = __popcll(pm & (((unsigned long long)2 << t) - 1ull)) - 1;

        if (t < NBOX && pres &&  ts) atomicAdd(&l_sh[mj], ssum);
        if (t < NBOX && pres && !ts) { atomicAdd(&l_ih[idx], ssum); l_isem[idx] = semv; }
    }
    __syncthreads();

    if (t < 64) {
        bool spres = (t < NSTUFF) && (l_sh[t] > 0);
        unsigned long long sm = __ballot(spres);
        const int nst = __popcll(sm);
        bool ipres = (t < NBOX) && (l_ih[t] > 0);
        unsigned long long im = __ballot(ipres);

        auto srank = [&](int c) { return __popcll(sm & (((unsigned long long)2 << c) - 1ull)) - 1; };
        auto irank = [&](int j) { return __popcll(im & (((unsigned long long)2 << j) - 1ull)) - 1; };

        if (t < NSTUFF) slut[t] = 1 + srank(t);
        if (t < NBOX) {
            int q2 = idx < 0 ? 0 : idx;
            slut[NSTUFF + t] = ts ? (1 + srank(mj)) : (1 + nst + irank(q2));
        }
        if (spres) l_co[1 + srank(t)] = t;
        if (ipres) l_co[1 + nst + irank(t)] = l_isem[t];
    }
    __syncthreads();

    int4 o;
    o.x = slut[v.x];
    o.y = slut[v.y];
    o.z = slut[v.z];
    o.w = slut[v.w];
    ((int4*)out)[q] = o;

    if (blockIdx.x == 0 && t < LL) {
        int* ocls = out + (size_t)BB * NPIX + b * LL;
        int* ocrd = out + (size_t)BB * NPIX + BB * LL + b * LL;
        ocls[t] = l_co[t];
        ocrd[t] = 0;
    }
}

extern "C" void kernel_launch(void* const* d_in, const int* in_sizes, int n_in,
                              void* d_out, int out_size, void* d_ws, size_t ws_size,
                              hipStream_t stream) {
    (void)in_sizes; (void)n_in; (void)out_size; (void)ws_size;
    const float* sem = (const float*)d_in[0];
    const float* roi = (const float*)d_in[1];
    const float* bbx = (const float*)d_in[2];
    const int*   cls = (const int*)d_in[3];
    int* out = (int*)d_out;

    int* counts = (int*)d_ws;                        // [B][32][10]
    int* stuffh = counts + BB * NBOX * NCLS;         // [B][6]
    // 652 ints = 2608 B (16B-aligned); pred bytes follow
    uchar4* pred8 = (uchar4*)(stuffh + BB * NSTUFF); // [B*NPIX] bytes

    hipMemsetAsync(d_ws, 0, (BB * NBOX * NCLS + BB * NSTUFF) * sizeof(int), stream);

    dim3 g1(NTILES, BB);
    k_fuse<<<g1, 256, 0, stream>>>(sem, roi, bbx, cls, pred8, counts, stuffh);
    dim3 g2(NPIX / 1024, BB);   // 528 blocks/batch, 256 thr x 4 px
    k_relabel<<<g2, 256, 0, stream>>>(counts, stuffh, cls, pred8, out);
}

// Round 5
// 105.179 us; speedup vs baseline: 1.1857x; 1.0466x over previous
//
#include <hip/hip_runtime.h>
#include <math.h>

#define NSTUFF 6
#define NCLS   10          // N_STUFF + N_THING
#define NBOX   32
#define NTHING 4
#define RR     28
#define HH     768
#define WW     704
#define NPIX   (HH * WW)   // 540672
#define BB     2
#define LL     (1 + NSTUFF + NBOX)   // 39
#define NEGV   (-100.0f)

// Tile 64x16, 1056 blocks. History:
//   R6: 256 thr / 4 px = 108.6-109.6 us end-to-end (best so far)
//   R7: 64x8 / 128 thr / 4224 blocks REGRESSED (per-block fixed cost x4)
//   R8/R10: box-outer restructure REGRESSED (124.7/120.7) - VALU was never
//           the bottleneck (14% busy)
//   R11: launch_bounds(256,4) NEUTRAL (110.1) - VGPR cap wasn't the limiter
//   R12 (this): 512 thr / 2 px, SAME 1056 blocks. Halves per-thread serial
//        doPix chain depth (2 instead of 4 box-loop chains) and doubles
//        waves/CU (16 -> 32 cap) for latency hiding. Block count unchanged
//        so R7's per-block-overhead trap does not apply.
#define TW 64
#define TH 16
#define TILES_X (WW / TW)            // 11
#define TILES_Y (HH / TH)            // 48
#define NTILES  (TILES_X * TILES_Y)  // 528 per batch
#define NHIST   (NBOX * NCLS + NSTUFF)
#define NTHR    512

__device__ __forceinline__ float sigmoidf_(float x) {
    return 1.0f / (1.0f + expf(-x));
}

// ---------------------------------------------------------------------------
// K1: tiled fused logits + argmax + histograms. 2 px/thread via float2 sem
// loads (all 10 channels upfront -> one latency round). Per-tile box cull
// in-register by wave 0. Winner index (0..37) stored as uchar2 into ws
// (byte layout identical to the uchar4 path -> k_relabel unchanged).
// Sequential-argmax semantics preserved via the gap rule (skipped boxes
// contribute exactly -0.0f; only the first box of a skipped run can win, and
// only while bv < 0).
// ---------------------------------------------------------------------------
__global__ __launch_bounds__(NTHR) void k_fuse(
    const float* __restrict__ sem,   // [B][10][H][W]
    const float* __restrict__ roi,   // [B][32][4][28][28]
    const float* __restrict__ bbx,   // [B][32][4]
    const int*   __restrict__ cls,   // [B][32]
    uchar2*      __restrict__ pred8, // ws region, [B][H][W] bytes as uchar2
    int*         __restrict__ counts,
    int*         __restrict__ stuffh)
{
    const int b = blockIdx.y;
    __shared__ int   sh_y0[NBOX], sh_x0[NBOX], sh_yme[NBOX], sh_xme[NBOX];
    __shared__ int   sh_yie[NBOX], sh_xie[NBOX], sh_moff[NBOX], sh_cls[NBOX];
    __shared__ float sh_y0f[NBOX], sh_x0f[NBOX], sh_sy[NBOX], sh_sx[NBOX];
    __shared__ int   sh_list[NBOX];
    __shared__ int   sh_nbox;
    __shared__ int   sh_cnt[NHIST];

    const int t = threadIdx.x;
    const int tile = blockIdx.x;
    const int tx0 = (tile % TILES_X) * TW;
    const int ty0 = (tile / TILES_X) * TH;

    const int xq = tx0 + (t & 31) * 2;      // first of this thread's 2 pixels
    const int y  = ty0 + (t >> 5);
    const int p  = y * WW + xq;

    // All 10 channels upfront as float2 (independent loads, one latency round)
    const float* semb = sem + (size_t)b * NCLS * NPIX;
    float2 s2[NCLS];
    #pragma unroll
    for (int c = 0; c < NCLS; ++c)
        s2[c] = *(const float2*)(semb + (size_t)c * NPIX + p);

    for (int i = t; i < NHIST; i += NTHR) sh_cnt[i] = 0;

    // wave 0: per-box setup + in-register tile cull
    if (t < 64) {
        bool flag = false;
        if (t < NBOX) {
            const float* bbp = bbx + ((size_t)b * NBOX + t) * 4;
            float y0f = bbp[0], x0f = bbp[1], y1f = bbp[2], x1f = bbp[3];
            int y0 = (int)floorf(y0f), x0 = (int)floorf(x0f);
            int y1 = (int)floorf(y1f), x1 = (int)floorf(x1f);
            int yme = min(y1 + 1, HH), xme = min(x1 + 1, WW);
            int yie = (int)rintf(y1f) + 1, xie = (int)rintf(x1f) + 1;
            sh_y0[t] = y0;  sh_x0[t] = x0;
            sh_yme[t] = yme; sh_xme[t] = xme;
            sh_yie[t] = yie; sh_xie[t] = xie;
            sh_y0f[t] = (float)y0; sh_x0f[t] = (float)x0;
            float hh = (float)max(y1 - y0 + 1, 1);
            float ww = (float)max(x1 - x0 + 1, 1);
            sh_sy[t] = 28.0f / hh;  sh_sx[t] = 28.0f / ww;
            int c = cls[b * NBOX + t];
            sh_cls[t] = c;
            sh_moff[t] = (((b * NBOX + t) * NTHING) + c) * (RR * RR);
            int uy = max(yme, yie), ux = max(xme, xie);
            flag = (y0 < ty0 + TH) && (uy > ty0) && (x0 < tx0 + TW) && (ux > tx0);
        }
        unsigned long long m = __ballot(flag);
        if (flag) {
            int pos = __popcll(m & (((unsigned long long)1 << t) - 1ull));
            sh_list[pos] = t;
        }
        if (t == 0) sh_nbox = __popcll(m);
    }
    __syncthreads();

    const int nb = sh_nbox;

    auto doPix = [&](const float* s, int y_, int x_, int& bi_o, int& sp_o) {
        const float yf = (float)y_, xf = (float)x_;
        // sem_pred: full 10-channel argmax, first-occurrence ties
        float sb = s[0]; int sp = 0;
        #pragma unroll
        for (int c = 1; c < NCLS; ++c) if (s[c] > sb) { sb = s[c]; sp = c; }

        // stuff argmax
        float bv = s[0]; int bi = 0;
        #pragma unroll
        for (int c = 1; c < NSTUFF; ++c) if (s[c] > bv) { bv = s[c]; bi = c; }

        int prev = -1;
        for (int j = 0; j < nb; ++j) {
            const int n = sh_list[j];
            if (n > prev + 1 && bv < 0.0f) { bv = -0.0f; bi = NSTUFF + prev + 1; }
            const bool in_m = (y_ >= max(sh_y0[n], 0)) & (y_ < sh_yme[n]) &
                              (x_ >= max(sh_x0[n], 0)) & (x_ < sh_xme[n]);
            const bool in_i = (y_ >= sh_y0[n]) & (y_ < sh_yie[n]) &
                              (x_ >= sh_x0[n]) & (x_ < sh_xie[n]);
            float v;
            if (in_m | in_i) {
                float pm = NEGV;
                if (in_m) {
                    float sy = __fsub_rn(__fmul_rn(__fadd_rn(__fsub_rn(yf, sh_y0f[n]), 0.5f), sh_sy[n]), 0.5f);
                    sy = fminf(fmaxf(sy, 0.0f), 27.0f);
                    int ylo = (int)sy;
                    int yhi = min(ylo + 1, RR - 1);
                    float wy = __fsub_rn(sy, (float)ylo);
                    float sx = __fsub_rn(__fmul_rn(__fadd_rn(__fsub_rn(xf, sh_x0f[n]), 0.5f), sh_sx[n]), 0.5f);
                    sx = fminf(fmaxf(sx, 0.0f), 27.0f);
                    int xlo = (int)sx;
                    int xhi = min(xlo + 1, RR - 1);
                    float wx = __fsub_rn(sx, (float)xlo);
                    const float* m = roi + sh_moff[n];
                    float m00 = m[ylo * RR + xlo], m01 = m[ylo * RR + xhi];
                    float m10 = m[yhi * RR + xlo], m11 = m[yhi * RR + xhi];
                    float omy = __fsub_rn(1.0f, wy), omx = __fsub_rn(1.0f, wx);
                    float rl = __fadd_rn(__fmul_rn(m00, omy), __fmul_rn(m10, wy));
                    float rh = __fadd_rn(__fmul_rn(m01, omy), __fmul_rn(m11, wy));
                    pm = __fadd_rn(__fmul_rn(rl, omx), __fmul_rn(rh, wx));
                }
                float pi = NEGV;
                if (in_i) {
                    int c = sh_cls[n];
                    pi = (c == 0) ? s[6] : (c == 1) ? s[7] : (c == 2) ? s[8] : s[9];
                }
                v = __fmul_rn(__fadd_rn(sigmoidf_(pi), sigmoidf_(pm)), __fadd_rn(pi, pm));
            } else {
                v = -0.0f;
            }
            if (v > bv) { bv = v; bi = NSTUFF + n; }
            prev = n;
        }
        if (prev < NBOX - 1 && bv < 0.0f) { bi = NSTUFF + prev + 1; }
        bi_o = bi; sp_o = sp;
    };

    int bis[2], sps[2];
    #pragma unroll
    for (int j = 0; j < 2; ++j) {
        float s[NCLS];
        #pragma unroll
        for (int c = 0; c < NCLS; ++c) s[c] = ((const float*)&s2[c])[j];
        doPix(s, y, xq + j, bis[j], sps[j]);
    }

    uchar2 pv;
    pv.x = (unsigned char)bis[0]; pv.y = (unsigned char)bis[1];
    pred8[((size_t)b * NPIX + p) >> 1] = pv;

    // histogram: ballot-aggregate stuff bins; scatter-atomic instance pixels
    const int lane = t & 63;
    #pragma unroll
    for (int s = 0; s < NSTUFF; ++s) {
        int c = 0;
        #pragma unroll
        for (int j = 0; j < 2; ++j) c += __popcll(__ballot(bis[j] == s));
        if (lane == 0 && c) atomicAdd(&sh_cnt[NBOX * NCLS + s], c);
    }
    #pragma unroll
    for (int j = 0; j < 2; ++j)
        if (bis[j] >= NSTUFF) atomicAdd(&sh_cnt[(bis[j] - NSTUFF) * NCLS + sps[j]], 1);

    __syncthreads();
    for (int i = t; i < NHIST; i += NTHR) {
        int v = sh_cnt[i];
        if (v) {
            if (i < NBOX * NCLS) atomicAdd(&counts[b * NBOX * NCLS + i], v);
            else                 atomicAdd(&stuffh[b * NSTUFF + (i - NBOX * NCLS)], v);
        }
    }
}

// ---------------------------------------------------------------------------
// K2: fused label + seam remap. Pred bytes are loaded BEFORE the LUT barrier
// (independent of it) so wave-0's LUT recompute latency is hidden behind the
// global load. Ranks are pure functions of ballot masks. Block (0,b) also
// writes po_cls / po_iscrowd.
// ---------------------------------------------------------------------------
__global__ __launch_bounds__(256) void k_relabel(
    const int*    __restrict__ counts,
    const int*    __restrict__ stuffh,
    const int*    __restrict__ cls,
    const uchar4* __restrict__ pred8,
    int*          __restrict__ out)
{
    const int b = blockIdx.y;
    const int t = threadIdx.x;
    __shared__ int slut[NSTUFF + NBOX];
    __shared__ int l_sh[NSTUFF];
    __shared__ int l_ih[NBOX];
    __shared__ int l_isem[NBOX];
    __shared__ int l_co[LL];

    // issue the pred load first (independent of the LUT)
    const size_t q = (size_t)b * (NPIX / 4) + (size_t)blockIdx.x * 256 + t;
    const uchar4 v = pred8[q];

    int  ssum = 0, mj = 0, semv = 0, idx = -1;
    bool pres = false, ts = false;

    if (t < 64) {
        if (t < NSTUFF) l_sh[t] = stuffh[b * NSTUFF + t];
        if (t < NBOX)  { l_ih[t] = 0; l_isem[t] = 255; }
        if (t < LL)      l_co[t] = 255;

        if (t < NBOX) {
            const int* C = counts + ((size_t)b * NBOX + t) * NCLS;
            int c[NCLS];
            #pragma unroll
            for (int i = 0; i < NCLS; ++i) c[i] = C[i];
            int m = c[0]; mj = 0; ssum = c[0];
            #pragma unroll
            for (int i = 1; i < NCLS; ++i) {
                ssum += c[i];
                if (c[i] > m) { m = c[i]; mj = i; }
            }
            pres = ssum > 0;
            int thing = cls[b * NBOX + t] + NSTUFF;
            ts = pres && (mj != thing) && (2 * m >= ssum) && (mj < NSTUFF);
            semv = ts ? mj : thing;
        }
        unsigned long long pm = __ballot(pres);
        idx = __popcll(pm & (((unsigned long long)2 << t) - 1ull)) - 1;

        if (t < NBOX && pres &&  ts) atomicAdd(&l_sh[mj], ssum);
        if (t < NBOX && pres && !ts) { atomicAdd(&l_ih[idx], ssum); l_isem[idx] = semv; }
    }
    __syncthreads();

    if (t < 64) {
        bool spres = (t < NSTUFF) && (l_sh[t] > 0);
        unsigned long long sm = __ballot(spres);
        const int nst = __popcll(sm);
        bool ipres = (t < NBOX) && (l_ih[t] > 0);
        unsigned long long im = __ballot(ipres);

        auto srank = [&](int c) { return __popcll(sm & (((unsigned long long)2 << c) - 1ull)) - 1; };
        auto irank = [&](int j) { return __popcll(im & (((unsigned long long)2 << j) - 1ull)) - 1; };

        if (t < NSTUFF) slut[t] = 1 + srank(t);
        if (t < NBOX) {
            int q2 = idx < 0 ? 0 : idx;
            slut[NSTUFF + t] = ts ? (1 + srank(mj)) : (1 + nst + irank(q2));
        }
        if (spres) l_co[1 + srank(t)] = t;
        if (ipres) l_co[1 + nst + irank(t)] = l_isem[t];
    }
    __syncthreads();

    int4 o;
    o.x = slut[v.x];
    o.y = slut[v.y];
    o.z = slut[v.z];
    o.w = slut[v.w];
    ((int4*)out)[q] = o;

    if (blockIdx.x == 0 && t < LL) {
        int* ocls = out + (size_t)BB * NPIX + b * LL;
        int* ocrd = out + (size_t)BB * NPIX + BB * LL + b * LL;
        ocls[t] = l_co[t];
        ocrd[t] = 0;
    }
}

extern "C" void kernel_launch(void* const* d_in, const int* in_sizes, int n_in,
                              void* d_out, int out_size, void* d_ws, size_t ws_size,
                              hipStream_t stream) {
    (void)in_sizes; (void)n_in; (void)out_size; (void)ws_size;
    const float* sem = (const float*)d_in[0];
    const float* roi = (const float*)d_in[1];
    const float* bbx = (const float*)d_in[2];
    const int*   cls = (const int*)d_in[3];
    int* out = (int*)d_out;

    int* counts = (int*)d_ws;                        // [B][32][10]
    int* stuffh = counts + BB * NBOX * NCLS;         // [B][6]
    // 652 ints = 2608 B (16B-aligned); pred bytes follow
    uchar2* pred8 = (uchar2*)(stuffh + BB * NSTUFF); // [B*NPIX] bytes

    hipMemsetAsync(d_ws, 0, (BB * NBOX * NCLS + BB * NSTUFF) * sizeof(int), stream);

    dim3 g1(NTILES, BB);
    k_fuse<<<g1, NTHR, 0, stream>>>(sem, roi, bbx, cls, pred8, counts, stuffh);
    dim3 g2(NPIX / 1024, BB);   // 528 blocks/batch, 256 thr x 4 px
    k_relabel<<<g2, 256, 0, stream>>>(counts, stuffh, cls, (const uchar4*)pred8, out);
}

// Round 6
// 104.018 us; speedup vs baseline: 1.1989x; 1.0112x over previous
//
#include <hip/hip_runtime.h>
#include <math.h>

#define NSTUFF 6
#define NCLS   10          // N_STUFF + N_THING
#define NBOX   32
#define NTHING 4
#define RR     28
#define HH     768
#define WW     704
#define NPIX   (HH * WW)   // 540672
#define BB     2
#define LL     (1 + NSTUFF + NBOX)   // 39
#define NEGV   (-100.0f)

// Tile 64x16, 1056 blocks. History:
//   R6: 256 thr / 4 px = 108.6 us end-to-end
//   R7: 64x8 / 128 thr / 4224 blocks REGRESSED (per-block fixed cost x4)
//   R8/R10: box-outer restructure REGRESSED (124.7/120.7) — VALU never the
//           bottleneck (14% busy)
//   R11: launch_bounds(256,4) NEUTRAL (110.1) — VGPR cap not the limiter
//   R12: 512 thr / 2 px, same 1056 blocks = 105.2 (WIN: shorter chains +
//        32 waves/CU)
//   R13 (this): 1024 thr / 1 px, same 1056 blocks. Minimum per-thread chain
//        depth (one box-loop), same occupancy cap, same block count. End of
//        this lever's range.
#define TW 64
#define TH 16
#define TILES_X (WW / TW)            // 11
#define TILES_Y (HH / TH)            // 48
#define NTILES  (TILES_X * TILES_Y)  // 528 per batch
#define NHIST   (NBOX * NCLS + NSTUFF)
#define NTHR    1024

__device__ __forceinline__ float sigmoidf_(float x) {
    return 1.0f / (1.0f + expf(-x));
}

// ---------------------------------------------------------------------------
// K1: tiled fused logits + argmax + histograms. 1 px/thread; 10 independent
// scalar sem loads (64x4B = fully coalesced per wave), one latency round.
// Per-tile box cull in-register by wave 0. Winner index (0..37) stored as a
// byte (layout identical to the uchar4 path -> k_relabel unchanged).
// Sequential-argmax semantics preserved via the gap rule (skipped boxes
// contribute exactly -0.0f; only the first box of a skipped run can win, and
// only while bv < 0; -0.0f < 0.0f is false so a claim happens at most once
// per run).
// ---------------------------------------------------------------------------
__global__ __launch_bounds__(NTHR) void k_fuse(
    const float* __restrict__ sem,   // [B][10][H][W]
    const float* __restrict__ roi,   // [B][32][4][28][28]
    const float* __restrict__ bbx,   // [B][32][4]
    const int*   __restrict__ cls,   // [B][32]
    unsigned char* __restrict__ pred8, // ws region, [B][H][W] bytes
    int*         __restrict__ counts,
    int*         __restrict__ stuffh)
{
    const int b = blockIdx.y;
    __shared__ int   sh_y0[NBOX], sh_x0[NBOX], sh_yme[NBOX], sh_xme[NBOX];
    __shared__ int   sh_yie[NBOX], sh_xie[NBOX], sh_moff[NBOX], sh_cls[NBOX];
    __shared__ float sh_y0f[NBOX], sh_x0f[NBOX], sh_sy[NBOX], sh_sx[NBOX];
    __shared__ int   sh_list[NBOX];
    __shared__ int   sh_nbox;
    __shared__ int   sh_cnt[NHIST];

    const int t = threadIdx.x;
    const int tile = blockIdx.x;
    const int tx0 = (tile % TILES_X) * TW;
    const int ty0 = (tile / TILES_X) * TH;

    const int x = tx0 + (t & 63);           // this thread's single pixel
    const int y = ty0 + (t >> 6);
    const int p = y * WW + x;

    // All 10 channels upfront (independent scalar loads, one latency round)
    const float* semb = sem + (size_t)b * NCLS * NPIX;
    float s[NCLS];
    #pragma unroll
    for (int c = 0; c < NCLS; ++c)
        s[c] = semb[(size_t)c * NPIX + p];

    for (int i = t; i < NHIST; i += NTHR) sh_cnt[i] = 0;

    // wave 0: per-box setup + in-register tile cull
    if (t < 64) {
        bool flag = false;
        if (t < NBOX) {
            const float* bbp = bbx + ((size_t)b * NBOX + t) * 4;
            float y0f = bbp[0], x0f = bbp[1], y1f = bbp[2], x1f = bbp[3];
            int y0 = (int)floorf(y0f), x0 = (int)floorf(x0f);
            int y1 = (int)floorf(y1f), x1 = (int)floorf(x1f);
            int yme = min(y1 + 1, HH), xme = min(x1 + 1, WW);
            int yie = (int)rintf(y1f) + 1, xie = (int)rintf(x1f) + 1;
            sh_y0[t] = y0;  sh_x0[t] = x0;
            sh_yme[t] = yme; sh_xme[t] = xme;
            sh_yie[t] = yie; sh_xie[t] = xie;
            sh_y0f[t] = (float)y0; sh_x0f[t] = (float)x0;
            float hh = (float)max(y1 - y0 + 1, 1);
            float ww = (float)max(x1 - x0 + 1, 1);
            sh_sy[t] = 28.0f / hh;  sh_sx[t] = 28.0f / ww;
            int c = cls[b * NBOX + t];
            sh_cls[t] = c;
            sh_moff[t] = (((b * NBOX + t) * NTHING) + c) * (RR * RR);
            int uy = max(yme, yie), ux = max(xme, xie);
            flag = (y0 < ty0 + TH) && (uy > ty0) && (x0 < tx0 + TW) && (ux > tx0);
        }
        unsigned long long m = __ballot(flag);
        if (flag) {
            int pos = __popcll(m & (((unsigned long long)1 << t) - 1ull));
            sh_list[pos] = t;
        }
        if (t == 0) sh_nbox = __popcll(m);
    }
    __syncthreads();

    const int nb = sh_nbox;
    const float yf = (float)y, xf = (float)x;

    // sem_pred: full 10-channel argmax, first-occurrence ties
    float sb = s[0]; int sp = 0;
    #pragma unroll
    for (int c = 1; c < NCLS; ++c) if (s[c] > sb) { sb = s[c]; sp = c; }

    // stuff argmax
    float bv = s[0]; int bi = 0;
    #pragma unroll
    for (int c = 1; c < NSTUFF; ++c) if (s[c] > bv) { bv = s[c]; bi = c; }

    int prev = -1;
    for (int j = 0; j < nb; ++j) {
        const int n = sh_list[j];
        if (n > prev + 1 && bv < 0.0f) { bv = -0.0f; bi = NSTUFF + prev + 1; }
        const bool in_m = (y >= max(sh_y0[n], 0)) & (y < sh_yme[n]) &
                          (x >= max(sh_x0[n], 0)) & (x < sh_xme[n]);
        const bool in_i = (y >= sh_y0[n]) & (y < sh_yie[n]) &
                          (x >= sh_x0[n]) & (x < sh_xie[n]);
        float v;
        if (in_m | in_i) {
            float pm = NEGV;
            if (in_m) {
                float sy = __fsub_rn(__fmul_rn(__fadd_rn(__fsub_rn(yf, sh_y0f[n]), 0.5f), sh_sy[n]), 0.5f);
                sy = fminf(fmaxf(sy, 0.0f), 27.0f);
                int ylo = (int)sy;
                int yhi = min(ylo + 1, RR - 1);
                float wy = __fsub_rn(sy, (float)ylo);
                float sx = __fsub_rn(__fmul_rn(__fadd_rn(__fsub_rn(xf, sh_x0f[n]), 0.5f), sh_sx[n]), 0.5f);
                sx = fminf(fmaxf(sx, 0.0f), 27.0f);
                int xlo = (int)sx;
                int xhi = min(xlo + 1, RR - 1);
                float wx = __fsub_rn(sx, (float)xlo);
                const float* m = roi + sh_moff[n];
                float m00 = m[ylo * RR + xlo], m01 = m[ylo * RR + xhi];
                float m10 = m[yhi * RR + xlo], m11 = m[yhi * RR + xhi];
                float omy = __fsub_rn(1.0f, wy), omx = __fsub_rn(1.0f, wx);
                float rl = __fadd_rn(__fmul_rn(m00, omy), __fmul_rn(m10, wy));
                float rh = __fadd_rn(__fmul_rn(m01, omy), __fmul_rn(m11, wy));
                pm = __fadd_rn(__fmul_rn(rl, omx), __fmul_rn(rh, wx));
            }
            float pi = NEGV;
            if (in_i) {
                int c = sh_cls[n];
                pi = (c == 0) ? s[6] : (c == 1) ? s[7] : (c == 2) ? s[8] : s[9];
            }
            v = __fmul_rn(__fadd_rn(sigmoidf_(pi), sigmoidf_(pm)), __fadd_rn(pi, pm));
        } else {
            v = -0.0f;
        }
        if (v > bv) { bv = v; bi = NSTUFF + n; }
        prev = n;
    }
    if (prev < NBOX - 1 && bv < 0.0f) { bi = NSTUFF + prev + 1; }

    pred8[(size_t)b * NPIX + p] = (unsigned char)bi;

    // histogram: ballot-aggregate stuff bins; scatter-atomic instance pixels
    const int lane = t & 63;
    #pragma unroll
    for (int sc = 0; sc < NSTUFF; ++sc) {
        int c = __popcll(__ballot(bi == sc));
        if (lane == 0 && c) atomicAdd(&sh_cnt[NBOX * NCLS + sc], c);
    }
    if (bi >= NSTUFF) atomicAdd(&sh_cnt[(bi - NSTUFF) * NCLS + sp], 1);

    __syncthreads();
    for (int i = t; i < NHIST; i += NTHR) {
        int v = sh_cnt[i];
        if (v) {
            if (i < NBOX * NCLS) atomicAdd(&counts[b * NBOX * NCLS + i], v);
            else                 atomicAdd(&stuffh[b * NSTUFF + (i - NBOX * NCLS)], v);
        }
    }
}

// ---------------------------------------------------------------------------
// K2: fused label + seam remap. Pred bytes are loaded BEFORE the LUT barrier
// (independent of it) so wave-0's LUT recompute latency is hidden behind the
// global load. Ranks are pure functions of ballot masks. Block (0,b) also
// writes po_cls / po_iscrowd.
// ---------------------------------------------------------------------------
__global__ __launch_bounds__(256) void k_relabel(
    const int*    __restrict__ counts,
    const int*    __restrict__ stuffh,
    const int*    __restrict__ cls,
    const uchar4* __restrict__ pred8,
    int*          __restrict__ out)
{
    const int b = blockIdx.y;
    const int t = threadIdx.x;
    __shared__ int slut[NSTUFF + NBOX];
    __shared__ int l_sh[NSTUFF];
    __shared__ int l_ih[NBOX];
    __shared__ int l_isem[NBOX];
    __shared__ int l_co[LL];

    // issue the pred load first (independent of the LUT)
    const size_t q = (size_t)b * (NPIX / 4) + (size_t)blockIdx.x * 256 + t;
    const uchar4 v = pred8[q];

    int  ssum = 0, mj = 0, semv = 0, idx = -1;
    bool pres = false, ts = false;

    if (t < 64) {
        if (t < NSTUFF) l_sh[t] = stuffh[b * NSTUFF + t];
        if (t < NBOX)  { l_ih[t] = 0; l_isem[t] = 255; }
        if (t < LL)      l_co[t] = 255;

        if (t < NBOX) {
            const int* C = counts + ((size_t)b * NBOX + t) * NCLS;
            int c[NCLS];
            #pragma unroll
            for (int i = 0; i < NCLS; ++i) c[i] = C[i];
            int m = c[0]; mj = 0; ssum = c[0];
            #pragma unroll
            for (int i = 1; i < NCLS; ++i) {
                ssum += c[i];
                if (c[i] > m) { m = c[i]; mj = i; }
            }
            pres = ssum > 0;
            int thing = cls[b * NBOX + t] + NSTUFF;
            ts = pres && (mj != thing) && (2 * m >= ssum) && (mj < NSTUFF);
            semv = ts ? mj : thing;
        }
        unsigned long long pm = __ballot(pres);
        idx = __popcll(pm & (((unsigned long long)2 << t) - 1ull)) - 1;

        if (t < NBOX && pres &&  ts) atomicAdd(&l_sh[mj], ssum);
        if (t < NBOX && pres && !ts) { atomicAdd(&l_ih[idx], ssum); l_isem[idx] = semv; }
    }
    __syncthreads();

    if (t < 64) {
        bool spres = (t < NSTUFF) && (l_sh[t] > 0);
        unsigned long long sm = __ballot(spres);
        const int nst = __popcll(sm);
        bool ipres = (t < NBOX) && (l_ih[t] > 0);
        unsigned long long im = __ballot(ipres);

        auto srank = [&](int c) { return __popcll(sm & (((unsigned long long)2 << c) - 1ull)) - 1; };
        auto irank = [&](int j) { return __popcll(im & (((unsigned long long)2 << j) - 1ull)) - 1; };

        if (t < NSTUFF) slut[t] = 1 + srank(t);
        if (t < NBOX) {
            int q2 = idx < 0 ? 0 : idx;
            slut[NSTUFF + t] = ts ? (1 + srank(mj)) : (1 + nst + irank(q2));
        }
        if (spres) l_co[1 + srank(t)] = t;
        if (ipres) l_co[1 + nst + irank(t)] = l_isem[t];
    }
    __syncthreads();

    int4 o;
    o.x = slut[v.x];
    o.y = slut[v.y];
    o.z = slut[v.z];
    o.w = slut[v.w];
    ((int4*)out)[q] = o;

    if (blockIdx.x == 0 && t < LL) {
        int* ocls = out + (size_t)BB * NPIX + b * LL;
        int* ocrd = out + (size_t)BB * NPIX + BB * LL + b * LL;
        ocls[t] = l_co[t];
        ocrd[t] = 0;
    }
}

extern "C" void kernel_launch(void* const* d_in, const int* in_sizes, int n_in,
                              void* d_out, int out_size, void* d_ws, size_t ws_size,
                              hipStream_t stream) {
    (void)in_sizes; (void)n_in; (void)out_size; (void)ws_size;
    const float* sem = (const float*)d_in[0];
    const float* roi = (const float*)d_in[1];
    const float* bbx = (const float*)d_in[2];
    const int*   cls = (const int*)d_in[3];
    int* out = (int*)d_out;

    int* counts = (int*)d_ws;                        // [B][32][10]
    int* stuffh = counts + BB * NBOX * NCLS;         // [B][6]
    // 652 ints = 2608 B (16B-aligned); pred bytes follow
    unsigned char* pred8 = (unsigned char*)(stuffh + BB * NSTUFF); // [B*NPIX]

    hipMemsetAsync(d_ws, 0, (BB * NBOX * NCLS + BB * NSTUFF) * sizeof(int), stream);

    dim3 g1(NTILES, BB);
    k_fuse<<<g1, NTHR, 0, stream>>>(sem, roi, bbx, cls, pred8, counts, stuffh);
    dim3 g2(NPIX / 1024, BB);   // 528 blocks/batch, 256 thr x 4 px
    k_relabel<<<g2, 256, 0, stream>>>(counts, stuffh, cls, (const uchar4*)pred8, out);
}